// Round 15
// baseline (345.961 us; speedup 1.0000x reference)
//
#include <hip/hip_runtime.h>
#include <stdint.h>

#define D_MODEL 768
#define D_FF    3072
#define NH      12
#define DK      64
#define BB      8
#define SS      1024
#define NTOK    (BB*SS)   // 8192
#define QST     2304      // fused qkv row stride

typedef float          f32x4  __attribute__((ext_vector_type(4)));
typedef __bf16         bf16x8 __attribute__((ext_vector_type(8)));
typedef unsigned short us8v   __attribute__((ext_vector_type(8)));
typedef unsigned short us4v   __attribute__((ext_vector_type(4)));

__device__ __forceinline__ unsigned short f2b(float f) {
  unsigned int u = __builtin_bit_cast(unsigned int, f);
  u = (u + 0x7fffu + ((u >> 16) & 1u)) >> 16;
  return (unsigned short)u;
}
__device__ __forceinline__ float b2f(unsigned short h) {
  unsigned int u = ((unsigned int)h) << 16;
  return __builtin_bit_cast(float, u);
}
__device__ __forceinline__ float exp2a(float x) {
  float r; asm("v_exp_f32 %0, %1" : "=v"(r) : "v"(x)); return r;
}
__device__ __forceinline__ unsigned int cvtpk(float lo, float hi) {
  unsigned int r;
  asm("v_cvt_pk_bf16_f32 %0, %1, %2" : "=v"(r) : "v"(lo), "v"(hi));
  return r;
}

// ---------------- fused weight cast: fp32 -> bf16 (RNE) --------------------
#define N4TOT 1769472
__global__ __launch_bounds__(256) void cast6_kernel(
    const float* __restrict__ s0, const float* __restrict__ s1,
    const float* __restrict__ s2, const float* __restrict__ s3,
    const float* __restrict__ s4, const float* __restrict__ s5,
    unsigned short* __restrict__ d0, unsigned short* __restrict__ d1,
    unsigned short* __restrict__ d2, unsigned short* __restrict__ d3,
    unsigned short* __restrict__ d4, unsigned short* __restrict__ d5) {
  int i = blockIdx.x * 256 + threadIdx.x;
  if (i >= N4TOT) return;
  const float* src; unsigned short* dst; int off;
  if (i < 147456)       { src = s0; dst = d0; off = i; }
  else if (i < 294912)  { src = s1; dst = d1; off = i - 147456; }
  else if (i < 442368)  { src = s2; dst = d2; off = i - 294912; }
  else if (i < 589824)  { src = s3; dst = d3; off = i - 442368; }
  else if (i < 1179648) { src = s4; dst = d4; off = i - 589824; }
  else                  { src = s5; dst = d5; off = i - 1179648; }
  float4 f = ((const float4*)src)[off];
  us4v o; o.x = f2b(f.x); o.y = f2b(f.y); o.z = f2b(f.z); o.w = f2b(f.w);
  *(us4v*)(dst + (size_t)off * 4) = o;
}

// ---------------- LayerNorm (torch quirk: std ddof=1, denom std+eps) -------
__global__ __launch_bounds__(256) void ln_kernel(const float* __restrict__ x,
                                                 const float* __restrict__ ga,
                                                 const float* __restrict__ gb,
                                                 unsigned short* __restrict__ y) {
  int row = blockIdx.x;
  const float* xr = x + (size_t)row * D_MODEL;
  int t = threadIdx.x, w = t >> 6, l = t & 63;
  float v0 = xr[t], v1 = xr[t + 256], v2 = xr[t + 512];
  float s = v0 + v1 + v2;
  #pragma unroll
  for (int off = 32; off; off >>= 1) s += __shfl_xor(s, off);
  __shared__ float red[4];
  __shared__ float stats[2];
  if (l == 0) red[w] = s;
  __syncthreads();
  if (t == 0) stats[0] = (red[0] + red[1] + red[2] + red[3]) * (1.0f / 768.0f);
  __syncthreads();
  float mean = stats[0];
  float d0 = v0 - mean, d1 = v1 - mean, d2 = v2 - mean;
  float ss = d0 * d0 + d1 * d1 + d2 * d2;
  #pragma unroll
  for (int off = 32; off; off >>= 1) ss += __shfl_xor(ss, off);
  __syncthreads();
  if (l == 0) red[w] = ss;
  __syncthreads();
  if (t == 0) {
    float tot = red[0] + red[1] + red[2] + red[3];
    stats[1] = 1.0f / (sqrtf(tot * (1.0f / 767.0f)) + 1e-6f);
  }
  __syncthreads();
  float inv = stats[1];
  unsigned short* yr = y + (size_t)row * D_MODEL;
  yr[t]       = f2b(ga[t]       * (d0 * inv) + gb[t]);
  yr[t + 256] = f2b(ga[t + 256] * (d1 * inv) + gb[t + 256]);
  yr[t + 512] = f2b(ga[t + 512] * (d2 * inv) + gb[t + 512]);
}

// ---------------- bf16 MFMA GEMM:  C[M,N] = A[M,K] @ W[N,K]^T + bias -------
// BM=128, BN=64, BK=64, 4 waves (each 32x64: MF=2, NF=4).
// A is REG-STAGED direct from global (prefetched 1 step ahead): lanes
// l=ql,16+ql,32+ql,48+ql read the same row at bytes {0,16,32,48} -> 16 full
// 64B lines per load, zero redundancy, no LDS for A. B stays GLDS+LDS with
// the proven both-sides XOR swizzle. LDS 48KB->16KB (occupancy 3->~5 blk/CU),
// ds_reads/step 12->8, GLDS/step 6->2.
#define GLDS(g, l) __builtin_amdgcn_global_load_lds( \
    (__attribute__((address_space(1))) const void*)(g), \
    (__attribute__((address_space(3))) void*)(l), 16, 0, 0)

__global__ __launch_bounds__(256) void gemm64(
    const unsigned short* __restrict__ A,   // [M][K] bf16
    const unsigned short* __restrict__ W,   // [N][K] bf16
    const float* __restrict__ biasA,        // [segw]
    const float* __restrict__ biasB,        // or nullptr
    const float* __restrict__ biasC,        // or nullptr
    int segw,
    const float* __restrict__ resid,        // [M][N] fp32 or nullptr
    float* __restrict__ outF,               // fp32 out or nullptr
    unsigned short* __restrict__ outB,      // bf16 out or nullptr
    int M, int N, int K, int relu) {
  constexpr int BK  = 64;
  constexpr int MF  = 2;                    // 16-row frags per wave
  constexpr int NF  = 4;                    // 16-col frags per wave
  constexpr int BSZ = 64 * BK;              // shorts per B buffer (8KB)
  __shared__ unsigned short Bs[2 * BSZ];
  int t = threadIdx.x;
  int w = t >> 6, l = t & 63;
  int brow = blockIdx.x * 128;
  int bcol = blockIdx.y * 64;
  int wr = w * 32;
  int ql = l & 15, g = l >> 4;

  // B staging: pre-swizzled global source (both-sides XOR, rule #21)
  int r5  = t >> 3;                         // local row 0..31 (i adds 32)
  int swz = (t & 7) ^ (r5 & 7);
  const unsigned short* gb0 = W + (size_t)(bcol + r5) * K + swz * 8;

  // A direct-to-reg row pointers (per m-frag)
  const unsigned short* ga0 = A + (size_t)(brow + wr + ql) * K + g * 8;
  const unsigned short* ga1 = ga0 + (size_t)16 * K;

  f32x4 acc[MF][NF];
  #pragma unroll
  for (int m = 0; m < MF; m++)
    #pragma unroll
    for (int n = 0; n < NF; n++)
      acc[m][n] = (f32x4){0.f, 0.f, 0.f, 0.f};

  const int nt = K / BK;

  auto stageB = [&](int ti, int buf) {
    int k0 = ti * BK;
    #pragma unroll
    for (int i = 0; i < 2; i++)
      GLDS(gb0 + k0 + (size_t)(32 * i) * K, Bs + buf * BSZ + i * 2048 + t * 8);
  };

  bf16x8 acur[MF][2], anxt[MF][2];
  auto loadA = [&](int ti, bf16x8 dst[MF][2]) {
    int k0 = ti * BK;
    #pragma unroll
    for (int h = 0; h < 2; h++) {
      dst[0][h] = *(const bf16x8*)(ga0 + k0 + h * 32);
      dst[1][h] = *(const bf16x8*)(ga1 + k0 + h * 32);
    }
  };

  stageB(0, 0);
  loadA(0, acur);
  __syncthreads();

  int cb = 0;
  for (int ti = 0; ti < nt; ti++) {
    if (ti + 1 < nt) { stageB(ti + 1, cb ^ 1); loadA(ti + 1, anxt); }
    #pragma unroll
    for (int h = 0; h < 2; h++) {
      bf16x8 bfv[NF];
      #pragma unroll
      for (int n = 0; n < NF; n++)
        bfv[n] = *(const bf16x8*)(Bs + cb * BSZ + (n * 16 + ql) * 64 +
                                  ((((h << 2) + g) ^ (l & 7)) << 3));
      #pragma unroll
      for (int m = 0; m < MF; m++)
        #pragma unroll
        for (int n = 0; n < NF; n++)
          acc[m][n] = __builtin_amdgcn_mfma_f32_16x16x32_bf16(acur[m][h], bfv[n], acc[m][n], 0, 0, 0);
    }
    if (ti + 1 < nt) {
      __syncthreads();
      #pragma unroll
      for (int m = 0; m < MF; m++)
        #pragma unroll
        for (int h = 0; h < 2; h++)
          acur[m][h] = anxt[m][h];
    }
    cb ^= 1;
  }

  #pragma unroll
  for (int n = 0; n < NF; n++) {
    int col = bcol + n * 16 + ql;
    int seg = col / segw, off = col - seg * segw;
    const float* bp = (seg == 0) ? biasA : ((seg == 1) ? biasB : biasC);
    float bv = bp[off];
    #pragma unroll
    for (int m = 0; m < MF; m++) {
      int row0 = brow + wr + m * 16 + g * 4;
      #pragma unroll
      for (int r = 0; r < 4; r++) {
        int row = row0 + r;
        float vacc = acc[m][n][r] + bv;
        if (resid) vacc += resid[(size_t)row * N + col];
        if (relu)  vacc = fmaxf(vacc, 0.f);
        if (outF)  outF[(size_t)row * N + col] = vacc;
        if (outB)  outB[(size_t)row * N + col] = f2b(vacc);
      }
    }
  }
}

// ---------------- MFMA flash attention (QBLK=128, no-max, fused mask) ------
// R14 kernel verbatim (passing, 263.5us build).
#define PPAD 72
#define KPAD 72
#define SM_C1 0.18033688011112043f    // 0.125 * log2(e)

__global__ __launch_bounds__(256) void attn_mfma(
    const unsigned short* __restrict__ qkv,  // [NTOK][2304]: q|k|v
    const int* __restrict__ mask,            // [B][S]
    unsigned short* __restrict__ ctx) {
  int bh = blockIdx.x;
  int qt = blockIdx.y;
  int b = bh / NH, h = bh % NH;
  int t = threadIdx.x, w = t >> 6, l = t & 63;
  int ql = l & 15, g = l >> 4;

  const unsigned short* kp = qkv + 768 + h * DK;
  const unsigned short* vp = qkv + 1536 + h * DK;

  __shared__ unsigned short Ks[4096];        // [64 key][64 d], XOR-swizzled
  __shared__ unsigned short Vt[64 * KPAD];   // [d][key]
  __shared__ unsigned short Ps[128 * PPAD];  // [q][key], wave-private rows
  __shared__ float mk01[64];                 // mask ? SM_C1 : 0
  __shared__ float lrw[4][2][16];

  int srow = t >> 3;            // chunk0 row (0..31); chunk1 adds 32
  int sblk = t & 7;
  int sb0  = sblk ^ (srow & 7);
  int sb1  = sblk ^ ((srow + 32) & 7);

  // ---- Q fragments direct from global (one-time) ----
  bf16x8 qf[2][2];
  {
    const unsigned short* qp = qkv + h * DK;
    size_t row0 = (size_t)(b * SS + qt * 128 + w * 32 + ql);
    #pragma unroll
    for (int s = 0; s < 2; s++)
      #pragma unroll
      for (int ks = 0; ks < 2; ks++)
        qf[s][ks] = *(const bf16x8*)(qp + (row0 + s * 16) * QST + ks * 32 + g * 8);
  }

  f32x4 acc_o[2][4];
  #pragma unroll
  for (int s = 0; s < 2; s++)
    #pragma unroll
    for (int nf = 0; nf < 4; nf++) acc_o[s][nf] = (f32x4){0.f, 0.f, 0.f, 0.f};
  float lrun[2] = {0.f, 0.f};

  for (int kt = 0; kt < 16; kt++) {
    size_t tok0 = (size_t)(b * SS + kt * 64);
    GLDS(kp + (tok0 + srow)      * QST + sb0 * 8, Ks + t * 8);
    GLDS(kp + (tok0 + srow + 32) * QST + sb1 * 8, Ks + 2048 + t * 8);
    {
      const unsigned short* vsrc = vp + (tok0 + l) * QST + w * 16;
      us8v v0 = *(const us8v*)vsrc;
      us8v v1 = *(const us8v*)(vsrc + 8);
      #pragma unroll
      for (int j = 0; j < 8; j++) {
        Vt[(w * 16 + j)     * KPAD + l] = v0[j];
        Vt[(w * 16 + 8 + j) * KPAD + l] = v1[j];
      }
    }
    if (t < 64) mk01[t] = mask[b * SS + kt * 64 + t] ? SM_C1 : 0.0f;
    __syncthreads();

    // ---- QK^T: both qsets, K-frags shared per ks chunk ----
    f32x4 sa[2][4];
    #pragma unroll
    for (int s = 0; s < 2; s++)
      #pragma unroll
      for (int kf = 0; kf < 4; kf++) sa[s][kf] = (f32x4){0.f, 0.f, 0.f, 0.f};
    #pragma unroll
    for (int ks = 0; ks < 2; ks++) {
      bf16x8 kfr[4];
      #pragma unroll
      for (int kf = 0; kf < 4; kf++) {
        int row = kf * 16 + ql;
        kfr[kf] = *(const bf16x8*)(Ks + row * 64 + ((g + 4 * ks) ^ (ql & 7)) * 8);
      }
      #pragma unroll
      for (int s = 0; s < 2; s++)
        #pragma unroll
        for (int kf = 0; kf < 4; kf++)
          sa[s][kf] = __builtin_amdgcn_mfma_f32_16x16x32_bf16(kfr[kf], qf[s][ks], sa[s][kf], 0, 0, 0);
    }

    // ---- hoisted mask multipliers (shared by both qsets) ----
    float mv[16];
    #pragma unroll
    for (int kf = 0; kf < 4; kf++)
      #pragma unroll
      for (int r = 0; r < 4; r++)
        mv[kf * 4 + r] = mk01[kf * 16 + g * 4 + r];

    // ---- softmax (no max, mask folded into multiplier), pack P -> LDS ----
    #pragma unroll
    for (int s = 0; s < 2; s++) {
      float pv[16];
      float rs = 0.f;
      #pragma unroll
      for (int i = 0; i < 16; i++) {
        pv[i] = exp2a(sa[s][i >> 2][i & 3] * mv[i]);
        rs += pv[i];
      }
      rs += __shfl_xor(rs, 16);
      rs += __shfl_xor(rs, 32);
      lrun[s] += rs;

      int prow = w * 32 + s * 16 + ql;
      #pragma unroll
      for (int kf = 0; kf < 4; kf++) {
        uint2 pk;
        pk.x = cvtpk(pv[kf * 4 + 0], pv[kf * 4 + 1]);
        pk.y = cvtpk(pv[kf * 4 + 2], pv[kf * 4 + 3]);
        *(uint2*)(Ps + prow * PPAD + kf * 16 + g * 4) = pk;
      }
    }

    // ---- PV: O += P . V (pure accumulate, no rescale) ----
    #pragma unroll
    for (int ks = 0; ks < 2; ks++) {
      bf16x8 vfr[4];
      #pragma unroll
      for (int nf = 0; nf < 4; nf++)
        vfr[nf] = *(const bf16x8*)(Vt + (ql + nf * 16) * KPAD + g * 8 + ks * 32);
      #pragma unroll
      for (int s = 0; s < 2; s++) {
        bf16x8 pa = *(const bf16x8*)(Ps + (w * 32 + s * 16 + ql) * PPAD + g * 8 + ks * 32);
        #pragma unroll
        for (int nf = 0; nf < 4; nf++)
          acc_o[s][nf] = __builtin_amdgcn_mfma_f32_16x16x32_bf16(pa, vfr[nf], acc_o[s][nf], 0, 0, 0);
      }
    }
    __syncthreads();
  }

  // ---- epilogue: divide by l, write ctx ----
  #pragma unroll
  for (int s = 0; s < 2; s++)
    if (l < 16) lrw[w][s][l] = lrun[s];
  #pragma unroll
  for (int s = 0; s < 2; s++) {
    float li0 = 1.0f / lrw[w][s][g * 4 + 0], li1 = 1.0f / lrw[w][s][g * 4 + 1];
    float li2 = 1.0f / lrw[w][s][g * 4 + 2], li3 = 1.0f / lrw[w][s][g * 4 + 3];
    #pragma unroll
    for (int nf = 0; nf < 4; nf++) {
      #pragma unroll
      for (int r = 0; r < 4; r++) {
        float li = (r == 0) ? li0 : (r == 1) ? li1 : (r == 2) ? li2 : li3;
        int tok = b * SS + qt * 128 + w * 32 + s * 16 + g * 4 + r;
        ctx[(size_t)tok * D_MODEL + h * DK + nf * 16 + ql] = f2b(acc_o[s][nf][r] * li);
      }
    }
  }
}

// ---------------------------------------------------------------------------
extern "C" void kernel_launch(void* const* d_in, const int* in_sizes, int n_in,
                              void* d_out, int out_size, void* d_ws, size_t ws_size,
                              hipStream_t stream) {
  const float* x    = (const float*)d_in[0];
  const int*   mask = (const int*)d_in[1];
  const float* wq   = (const float*)d_in[2];
  const float* bq   = (const float*)d_in[3];
  const float* wk   = (const float*)d_in[4];
  const float* bk   = (const float*)d_in[5];
  const float* wv   = (const float*)d_in[6];
  const float* bv   = (const float*)d_in[7];
  const float* wo   = (const float*)d_in[8];
  const float* bo   = (const float*)d_in[9];
  const float* ln1a = (const float*)d_in[10];
  const float* ln1b = (const float*)d_in[11];
  const float* ln2a = (const float*)d_in[12];
  const float* ln2b = (const float*)d_in[13];
  const float* w1   = (const float*)d_in[14];
  const float* b1   = (const float*)d_in[15];
  const float* w2   = (const float*)d_in[16];
  const float* b2   = (const float*)d_in[17];

  char* ws = (char*)d_ws;
  unsigned short* wqkvb = (unsigned short*)(ws + 0);
  unsigned short* wob   = (unsigned short*)(ws + 3538944);
  unsigned short* w1b   = (unsigned short*)(ws + 4718592);
  unsigned short* w2b   = (unsigned short*)(ws + 9437184);
  unsigned short* xnb   = (unsigned short*)(ws + 14155776);
  unsigned short* qkvb  = (unsigned short*)(ws + 26738688);
  unsigned short* ctxb  = (unsigned short*)(ws + 64487424);
  float*          x1    = (float*)(ws + 26738688);          // alias qkvb
  unsigned short* h1b   = (unsigned short*)(ws + 51904512); // alias qkv tail+ctx

  // 1. fused weight cast (wq/wk/wv concat into wqkvb rows 0/768/1536)
  cast6_kernel<<<N4TOT / 256, 256, 0, stream>>>(
      wq, wk, wv, wo, w1, w2,
      wqkvb, wqkvb + 589824, wqkvb + 1179648, wob, w1b, w2b);

  // 2. LN1
  ln_kernel<<<NTOK, 256, 0, stream>>>(x, ln1a, ln1b, xnb);

  // 3. fused QKV GEMM: [8192][2304]
  dim3 gqkv(NTOK / 128, QST / 64);
  gemm64<<<gqkv, 256, 0, stream>>>(xnb, wqkvb, bq, bk, bv, 768,
                                   nullptr, nullptr, qkvb,
                                   NTOK, QST, D_MODEL, 0);

  // 4. attention (MFMA flash, QBLK=128, 4 waves, no-max fused-mask softmax)
  dim3 ga(BB * NH, SS / 128);
  attn_mfma<<<ga, 256, 0, stream>>>(qkvb, mask, ctxb);

  // 5. WO + residual 1 -> x1 (fp32)
  dim3 gwo(NTOK / 128, D_MODEL / 64);
  gemm64<<<gwo, 256, 0, stream>>>(ctxb, wob, bo, nullptr, nullptr, D_MODEL,
                                  x, x1, nullptr,
                                  NTOK, D_MODEL, D_MODEL, 0);

  // 6. LN2
  ln_kernel<<<NTOK, 256, 0, stream>>>(x1, ln2a, ln2b, xnb);

  // 7. FF1 + ReLU -> h1 (bf16)
  dim3 gff(NTOK / 128, D_FF / 64);
  gemm64<<<gff, 256, 0, stream>>>(xnb, w1b, b1, nullptr, nullptr, D_FF,
                                  nullptr, nullptr, h1b,
                                  NTOK, D_FF, D_MODEL, 1);

  // 8. FF2 + residual 2 -> d_out (fp32)
  dim3 gff2(NTOK / 128, D_MODEL / 64);
  gemm64<<<gff2, 256, 0, stream>>>(h1b, w2b, b2, nullptr, nullptr, D_MODEL,
                                   x1, (float*)d_out, nullptr,
                                   NTOK, D_MODEL, D_FF, 0);
}

// Round 16
// 262.978 us; speedup vs baseline: 1.3156x; 1.3156x over previous
//
#include <hip/hip_runtime.h>
#include <stdint.h>

#define D_MODEL 768
#define D_FF    3072
#define NH      12
#define DK      64
#define BB      8
#define SS      1024
#define NTOK    (BB*SS)   // 8192
#define QST     2304      // fused qkv row stride

typedef float          f32x4  __attribute__((ext_vector_type(4)));
typedef __bf16         bf16x8 __attribute__((ext_vector_type(8)));
typedef unsigned short us8v   __attribute__((ext_vector_type(8)));
typedef unsigned short us4v   __attribute__((ext_vector_type(4)));

__device__ __forceinline__ unsigned short f2b(float f) {
  unsigned int u = __builtin_bit_cast(unsigned int, f);
  u = (u + 0x7fffu + ((u >> 16) & 1u)) >> 16;
  return (unsigned short)u;
}
__device__ __forceinline__ float b2f(unsigned short h) {
  unsigned int u = ((unsigned int)h) << 16;
  return __builtin_bit_cast(float, u);
}
__device__ __forceinline__ float exp2a(float x) {
  float r; asm("v_exp_f32 %0, %1" : "=v"(r) : "v"(x)); return r;
}
__device__ __forceinline__ unsigned int cvtpk(float lo, float hi) {
  unsigned int r;
  asm("v_cvt_pk_bf16_f32 %0, %1, %2" : "=v"(r) : "v"(lo), "v"(hi));
  return r;
}

// ---------------- fused weight cast: fp32 -> bf16 (RNE) --------------------
#define N4TOT 1769472
__global__ __launch_bounds__(256) void cast6_kernel(
    const float* __restrict__ s0, const float* __restrict__ s1,
    const float* __restrict__ s2, const float* __restrict__ s3,
    const float* __restrict__ s4, const float* __restrict__ s5,
    unsigned short* __restrict__ d0, unsigned short* __restrict__ d1,
    unsigned short* __restrict__ d2, unsigned short* __restrict__ d3,
    unsigned short* __restrict__ d4, unsigned short* __restrict__ d5) {
  int i = blockIdx.x * 256 + threadIdx.x;
  if (i >= N4TOT) return;
  const float* src; unsigned short* dst; int off;
  if (i < 147456)       { src = s0; dst = d0; off = i; }
  else if (i < 294912)  { src = s1; dst = d1; off = i - 147456; }
  else if (i < 442368)  { src = s2; dst = d2; off = i - 294912; }
  else if (i < 589824)  { src = s3; dst = d3; off = i - 442368; }
  else if (i < 1179648) { src = s4; dst = d4; off = i - 589824; }
  else                  { src = s5; dst = d5; off = i - 1179648; }
  float4 f = ((const float4*)src)[off];
  us4v o; o.x = f2b(f.x); o.y = f2b(f.y); o.z = f2b(f.z); o.w = f2b(f.w);
  *(us4v*)(dst + (size_t)off * 4) = o;
}

// ---------------- LayerNorm (torch quirk: std ddof=1, denom std+eps) -------
__global__ __launch_bounds__(256) void ln_kernel(const float* __restrict__ x,
                                                 const float* __restrict__ ga,
                                                 const float* __restrict__ gb,
                                                 unsigned short* __restrict__ y) {
  int row = blockIdx.x;
  const float* xr = x + (size_t)row * D_MODEL;
  int t = threadIdx.x, w = t >> 6, l = t & 63;
  float v0 = xr[t], v1 = xr[t + 256], v2 = xr[t + 512];
  float s = v0 + v1 + v2;
  #pragma unroll
  for (int off = 32; off; off >>= 1) s += __shfl_xor(s, off);
  __shared__ float red[4];
  __shared__ float stats[2];
  if (l == 0) red[w] = s;
  __syncthreads();
  if (t == 0) stats[0] = (red[0] + red[1] + red[2] + red[3]) * (1.0f / 768.0f);
  __syncthreads();
  float mean = stats[0];
  float d0 = v0 - mean, d1 = v1 - mean, d2 = v2 - mean;
  float ss = d0 * d0 + d1 * d1 + d2 * d2;
  #pragma unroll
  for (int off = 32; off; off >>= 1) ss += __shfl_xor(ss, off);
  __syncthreads();
  if (l == 0) red[w] = ss;
  __syncthreads();
  if (t == 0) {
    float tot = red[0] + red[1] + red[2] + red[3];
    stats[1] = 1.0f / (sqrtf(tot * (1.0f / 767.0f)) + 1e-6f);
  }
  __syncthreads();
  float inv = stats[1];
  unsigned short* yr = y + (size_t)row * D_MODEL;
  yr[t]       = f2b(ga[t]       * (d0 * inv) + gb[t]);
  yr[t + 256] = f2b(ga[t + 256] * (d1 * inv) + gb[t + 256]);
  yr[t + 512] = f2b(ga[t + 512] * (d2 * inv) + gb[t + 512]);
}

// ---------------- bf16 MFMA GEMM (R14 gemm_t<64> path, proven best) --------
// BM=128, BN=64, BK=64, 4 waves (each 32x64: MF=2, NF=4), 2-buffer GLDS
// pipeline for BOTH operands (staging stays out of the register file — R15's
// reg-staged A collapsed VGPR to 48 and serialized the loads).
// Both-sides XOR swizzle (rule #21) keeps 128B-row ds_read_b128 conflict-free.
#define GLDS(g, l) __builtin_amdgcn_global_load_lds( \
    (__attribute__((address_space(1))) const void*)(g), \
    (__attribute__((address_space(3))) void*)(l), 16, 0, 0)

__global__ __launch_bounds__(256) void gemm64(
    const unsigned short* __restrict__ A,   // [M][K] bf16
    const unsigned short* __restrict__ W,   // [N][K] bf16
    const float* __restrict__ biasA,        // [segw]
    const float* __restrict__ biasB,        // or nullptr
    const float* __restrict__ biasC,        // or nullptr
    int segw,
    const float* __restrict__ resid,        // [M][N] fp32 or nullptr
    float* __restrict__ outF,               // fp32 out or nullptr
    unsigned short* __restrict__ outB,      // bf16 out or nullptr
    int M, int N, int K, int relu) {
  constexpr int BK  = 64;
  constexpr int MF  = 2;                    // 16-row frags per wave
  constexpr int NF  = 4;                    // 16-col frags per wave
  constexpr int ASZ = 128 * BK;             // shorts per A buffer
  constexpr int BSZ = 64 * BK;              // shorts per B buffer
  __shared__ unsigned short As[2 * ASZ];
  __shared__ unsigned short Bs[2 * BSZ];
  int t = threadIdx.x;
  int w = t >> 6, l = t & 63;
  int brow = blockIdx.x * 128;
  int bcol = blockIdx.y * 64;
  int wr = w * 32;
  int ql = l & 15, g = l >> 4;

  int r5  = t >> 3;                         // local row 0..31 (groups add 32)
  int swz = (t & 7) ^ (r5 & 7);             // pre-swizzled source chunk
  const unsigned short* ga0 = A + (size_t)(brow + r5) * K + swz * 8;
  const unsigned short* gb0 = W + (size_t)(bcol + r5) * K + swz * 8;

  f32x4 acc[MF][NF];
  #pragma unroll
  for (int m = 0; m < MF; m++)
    #pragma unroll
    for (int n = 0; n < NF; n++)
      acc[m][n] = (f32x4){0.f, 0.f, 0.f, 0.f};

  const int nt = K / BK;

  auto stage = [&](int ti, int buf) {
    int k0 = ti * BK;
    #pragma unroll
    for (int i = 0; i < 4; i++)             // A: rows r5+32i, 16B each
      GLDS(ga0 + k0 + (size_t)(32 * i) * K, As + buf * ASZ + i * 2048 + t * 8);
    #pragma unroll
    for (int i = 0; i < 2; i++)             // B: rows r5+32i
      GLDS(gb0 + k0 + (size_t)(32 * i) * K, Bs + buf * BSZ + i * 2048 + t * 8);
  };

  stage(0, 0);
  __syncthreads();

  int cb = 0;
  for (int ti = 0; ti < nt; ti++) {
    if (ti + 1 < nt) stage(ti + 1, cb ^ 1);
    #pragma unroll
    for (int h = 0; h < 2; h++) {
      bf16x8 af[MF], bfv[NF];
      #pragma unroll
      for (int m = 0; m < MF; m++)
        af[m] = *(const bf16x8*)(As + cb * ASZ + (wr + m * 16 + ql) * 64 +
                                 ((((h << 2) + g) ^ (l & 7)) << 3));
      #pragma unroll
      for (int n = 0; n < NF; n++)
        bfv[n] = *(const bf16x8*)(Bs + cb * BSZ + (n * 16 + ql) * 64 +
                                  ((((h << 2) + g) ^ (l & 7)) << 3));
      #pragma unroll
      for (int m = 0; m < MF; m++)
        #pragma unroll
        for (int n = 0; n < NF; n++)
          acc[m][n] = __builtin_amdgcn_mfma_f32_16x16x32_bf16(af[m], bfv[n], acc[m][n], 0, 0, 0);
    }
    if (ti + 1 < nt) __syncthreads();
    cb ^= 1;
  }

  #pragma unroll
  for (int n = 0; n < NF; n++) {
    int col = bcol + n * 16 + ql;
    int seg = col / segw, off = col - seg * segw;
    const float* bp = (seg == 0) ? biasA : ((seg == 1) ? biasB : biasC);
    float bv = bp[off];
    #pragma unroll
    for (int m = 0; m < MF; m++) {
      int row0 = brow + wr + m * 16 + g * 4;
      #pragma unroll
      for (int r = 0; r < 4; r++) {
        int row = row0 + r;
        float vacc = acc[m][n][r] + bv;
        if (resid) vacc += resid[(size_t)row * N + col];
        if (relu)  vacc = fmaxf(vacc, 0.f);
        if (outF)  outF[(size_t)row * N + col] = vacc;
        if (outB)  outB[(size_t)row * N + col] = f2b(vacc);
      }
    }
  }
}

// ---------------- MFMA flash attention (QBLK=128, no-max, fused mask) ------
// R14 kernel verbatim (best: 263.5us build).
#define PPAD 72
#define KPAD 72
#define SM_C1 0.18033688011112043f    // 0.125 * log2(e)

__global__ __launch_bounds__(256) void attn_mfma(
    const unsigned short* __restrict__ qkv,  // [NTOK][2304]: q|k|v
    const int* __restrict__ mask,            // [B][S]
    unsigned short* __restrict__ ctx) {
  int bh = blockIdx.x;
  int qt = blockIdx.y;
  int b = bh / NH, h = bh % NH;
  int t = threadIdx.x, w = t >> 6, l = t & 63;
  int ql = l & 15, g = l >> 4;

  const unsigned short* kp = qkv + 768 + h * DK;
  const unsigned short* vp = qkv + 1536 + h * DK;

  __shared__ unsigned short Ks[4096];        // [64 key][64 d], XOR-swizzled
  __shared__ unsigned short Vt[64 * KPAD];   // [d][key]
  __shared__ unsigned short Ps[128 * PPAD];  // [q][key], wave-private rows
  __shared__ float mk01[64];                 // mask ? SM_C1 : 0
  __shared__ float lrw[4][2][16];

  int srow = t >> 3;            // chunk0 row (0..31); chunk1 adds 32
  int sblk = t & 7;
  int sb0  = sblk ^ (srow & 7);
  int sb1  = sblk ^ ((srow + 32) & 7);

  // ---- Q fragments direct from global (one-time) ----
  bf16x8 qf[2][2];
  {
    const unsigned short* qp = qkv + h * DK;
    size_t row0 = (size_t)(b * SS + qt * 128 + w * 32 + ql);
    #pragma unroll
    for (int s = 0; s < 2; s++)
      #pragma unroll
      for (int ks = 0; ks < 2; ks++)
        qf[s][ks] = *(const bf16x8*)(qp + (row0 + s * 16) * QST + ks * 32 + g * 8);
  }

  f32x4 acc_o[2][4];
  #pragma unroll
  for (int s = 0; s < 2; s++)
    #pragma unroll
    for (int nf = 0; nf < 4; nf++) acc_o[s][nf] = (f32x4){0.f, 0.f, 0.f, 0.f};
  float lrun[2] = {0.f, 0.f};

  for (int kt = 0; kt < 16; kt++) {
    size_t tok0 = (size_t)(b * SS + kt * 64);
    GLDS(kp + (tok0 + srow)      * QST + sb0 * 8, Ks + t * 8);
    GLDS(kp + (tok0 + srow + 32) * QST + sb1 * 8, Ks + 2048 + t * 8);
    {
      const unsigned short* vsrc = vp + (tok0 + l) * QST + w * 16;
      us8v v0 = *(const us8v*)vsrc;
      us8v v1 = *(const us8v*)(vsrc + 8);
      #pragma unroll
      for (int j = 0; j < 8; j++) {
        Vt[(w * 16 + j)     * KPAD + l] = v0[j];
        Vt[(w * 16 + 8 + j) * KPAD + l] = v1[j];
      }
    }
    if (t < 64) mk01[t] = mask[b * SS + kt * 64 + t] ? SM_C1 : 0.0f;
    __syncthreads();

    // ---- QK^T: both qsets, K-frags shared per ks chunk ----
    f32x4 sa[2][4];
    #pragma unroll
    for (int s = 0; s < 2; s++)
      #pragma unroll
      for (int kf = 0; kf < 4; kf++) sa[s][kf] = (f32x4){0.f, 0.f, 0.f, 0.f};
    #pragma unroll
    for (int ks = 0; ks < 2; ks++) {
      bf16x8 kfr[4];
      #pragma unroll
      for (int kf = 0; kf < 4; kf++) {
        int row = kf * 16 + ql;
        kfr[kf] = *(const bf16x8*)(Ks + row * 64 + ((g + 4 * ks) ^ (ql & 7)) * 8);
      }
      #pragma unroll
      for (int s = 0; s < 2; s++)
        #pragma unroll
        for (int kf = 0; kf < 4; kf++)
          sa[s][kf] = __builtin_amdgcn_mfma_f32_16x16x32_bf16(kfr[kf], qf[s][ks], sa[s][kf], 0, 0, 0);
    }

    // ---- hoisted mask multipliers (shared by both qsets) ----
    float mv[16];
    #pragma unroll
    for (int kf = 0; kf < 4; kf++)
      #pragma unroll
      for (int r = 0; r < 4; r++)
        mv[kf * 4 + r] = mk01[kf * 16 + g * 4 + r];

    // ---- softmax (no max, mask folded into multiplier), pack P -> LDS ----
    #pragma unroll
    for (int s = 0; s < 2; s++) {
      float pv[16];
      float rs = 0.f;
      #pragma unroll
      for (int i = 0; i < 16; i++) {
        pv[i] = exp2a(sa[s][i >> 2][i & 3] * mv[i]);
        rs += pv[i];
      }
      rs += __shfl_xor(rs, 16);
      rs += __shfl_xor(rs, 32);
      lrun[s] += rs;

      int prow = w * 32 + s * 16 + ql;
      #pragma unroll
      for (int kf = 0; kf < 4; kf++) {
        uint2 pk;
        pk.x = cvtpk(pv[kf * 4 + 0], pv[kf * 4 + 1]);
        pk.y = cvtpk(pv[kf * 4 + 2], pv[kf * 4 + 3]);
        *(uint2*)(Ps + prow * PPAD + kf * 16 + g * 4) = pk;
      }
    }

    // ---- PV: O += P . V (pure accumulate, no rescale) ----
    #pragma unroll
    for (int ks = 0; ks < 2; ks++) {
      bf16x8 vfr[4];
      #pragma unroll
      for (int nf = 0; nf < 4; nf++)
        vfr[nf] = *(const bf16x8*)(Vt + (ql + nf * 16) * KPAD + g * 8 + ks * 32);
      #pragma unroll
      for (int s = 0; s < 2; s++) {
        bf16x8 pa = *(const bf16x8*)(Ps + (w * 32 + s * 16 + ql) * PPAD + g * 8 + ks * 32);
        #pragma unroll
        for (int nf = 0; nf < 4; nf++)
          acc_o[s][nf] = __builtin_amdgcn_mfma_f32_16x16x32_bf16(pa, vfr[nf], acc_o[s][nf], 0, 0, 0);
      }
    }
    __syncthreads();
  }

  // ---- epilogue: divide by l, write ctx ----
  #pragma unroll
  for (int s = 0; s < 2; s++)
    if (l < 16) lrw[w][s][l] = lrun[s];
  #pragma unroll
  for (int s = 0; s < 2; s++) {
    float li0 = 1.0f / lrw[w][s][g * 4 + 0], li1 = 1.0f / lrw[w][s][g * 4 + 1];
    float li2 = 1.0f / lrw[w][s][g * 4 + 2], li3 = 1.0f / lrw[w][s][g * 4 + 3];
    #pragma unroll
    for (int nf = 0; nf < 4; nf++) {
      #pragma unroll
      for (int r = 0; r < 4; r++) {
        float li = (r == 0) ? li0 : (r == 1) ? li1 : (r == 2) ? li2 : li3;
        int tok = b * SS + qt * 128 + w * 32 + s * 16 + g * 4 + r;
        ctx[(size_t)tok * D_MODEL + h * DK + nf * 16 + ql] = f2b(acc_o[s][nf][r] * li);
      }
    }
  }
}

// ---------------------------------------------------------------------------
extern "C" void kernel_launch(void* const* d_in, const int* in_sizes, int n_in,
                              void* d_out, int out_size, void* d_ws, size_t ws_size,
                              hipStream_t stream) {
  const float* x    = (const float*)d_in[0];
  const int*   mask = (const int*)d_in[1];
  const float* wq   = (const float*)d_in[2];
  const float* bq   = (const float*)d_in[3];
  const float* wk   = (const float*)d_in[4];
  const float* bk   = (const float*)d_in[5];
  const float* wv   = (const float*)d_in[6];
  const float* bv   = (const float*)d_in[7];
  const float* wo   = (const float*)d_in[8];
  const float* bo   = (const float*)d_in[9];
  const float* ln1a = (const float*)d_in[10];
  const float* ln1b = (const float*)d_in[11];
  const float* ln2a = (const float*)d_in[12];
  const float* ln2b = (const float*)d_in[13];
  const float* w1   = (const float*)d_in[14];
  const float* b1   = (const float*)d_in[15];
  const float* w2   = (const float*)d_in[16];
  const float* b2   = (const float*)d_in[17];

  char* ws = (char*)d_ws;
  unsigned short* wqkvb = (unsigned short*)(ws + 0);
  unsigned short* wob   = (unsigned short*)(ws + 3538944);
  unsigned short* w1b   = (unsigned short*)(ws + 4718592);
  unsigned short* w2b   = (unsigned short*)(ws + 9437184);
  unsigned short* xnb   = (unsigned short*)(ws + 14155776);
  unsigned short* qkvb  = (unsigned short*)(ws + 26738688);
  unsigned short* ctxb  = (unsigned short*)(ws + 64487424);
  float*          x1    = (float*)(ws + 26738688);          // alias qkvb
  unsigned short* h1b   = (unsigned short*)(ws + 51904512); // alias qkv tail+ctx

  // 1. fused weight cast (wq/wk/wv concat into wqkvb rows 0/768/1536)
  cast6_kernel<<<N4TOT / 256, 256, 0, stream>>>(
      wq, wk, wv, wo, w1, w2,
      wqkvb, wqkvb + 589824, wqkvb + 1179648, wob, w1b, w2b);

  // 2. LN1
  ln_kernel<<<NTOK, 256, 0, stream>>>(x, ln1a, ln1b, xnb);

  // 3. fused QKV GEMM: [8192][2304]
  dim3 gqkv(NTOK / 128, QST / 64);
  gemm64<<<gqkv, 256, 0, stream>>>(xnb, wqkvb, bq, bk, bv, 768,
                                   nullptr, nullptr, qkvb,
                                   NTOK, QST, D_MODEL, 0);

  // 4. attention (MFMA flash, QBLK=128, 4 waves, no-max fused-mask softmax)
  dim3 ga(BB * NH, SS / 128);
  attn_mfma<<<ga, 256, 0, stream>>>(qkvb, mask, ctxb);

  // 5. WO + residual 1 -> x1 (fp32)
  dim3 gwo(NTOK / 128, D_MODEL / 64);
  gemm64<<<gwo, 256, 0, stream>>>(ctxb, wob, bo, nullptr, nullptr, D_MODEL,
                                  x, x1, nullptr,
                                  NTOK, D_MODEL, D_MODEL, 0);

  // 6. LN2
  ln_kernel<<<NTOK, 256, 0, stream>>>(x1, ln2a, ln2b, xnb);

  // 7. FF1 + ReLU -> h1 (bf16)
  dim3 gff(NTOK / 128, D_FF / 64);
  gemm64<<<gff, 256, 0, stream>>>(xnb, w1b, b1, nullptr, nullptr, D_FF,
                                  nullptr, nullptr, h1b,
                                  NTOK, D_FF, D_MODEL, 1);

  // 8. FF2 + residual 2 -> d_out (fp32)
  dim3 gff2(NTOK / 128, D_MODEL / 64);
  gemm64<<<gff2, 256, 0, stream>>>(h1b, w2b, b2, nullptr, nullptr, D_MODEL,
                                   x1, (float*)d_out, nullptr,
                                   NTOK, D_MODEL, D_FF, 0);
}